// Round 1
// baseline (19718.214 us; speedup 1.0000x reference)
//
#include <hip/hip_runtime.h>
#include <stdint.h>

// LSTMTimeDecoder on MI355X.
// Decomposition:
//   CW[b,g]  = C @ W_ih[:, :H]^T + (W_ih[:,H:] @ time_b) + b_ih + b_hh   (once)
//   u[g]     = W_ih[:,H:] @ time_W                                       (once)
//   gates_t  = h_t @ W_hh^T + CW + td[t]*u ;  LSTM cell ;  out[t] = h_{t+1} @ lin_W^T + lin_b
// Recurrence: 16 batch-groups x 16 hidden-slice wgs = 256 wgs (1/CU).
// Each wg: 16 batch rows x 32 h-cols, W_hh slice (128KB bf16) LDS-resident (XOR-swizzled),
// per-step h-slice exchange via device-scope counter among the 16 wgs of a group
// (blockIdx stride 16 => same XCD under round-robin mapping).

#define HD 512
#define BD 256
#define SD 512
#define OD 128

typedef __attribute__((ext_vector_type(8))) short short8;
typedef __attribute__((ext_vector_type(4))) float f32x4;

static __device__ __forceinline__ unsigned short f2bf(float x) {
  unsigned int u = __float_as_uint(x);
  u += 0x7fffu + ((u >> 16) & 1u);
  return (unsigned short)(u >> 16);
}
static __device__ __forceinline__ float sigm(float x) {
  return 1.0f / (1.0f + __expf(-x));
}
static __device__ __forceinline__ float tanhf_(float x) {
  x = fminf(15.f, fmaxf(-15.f, x));
  float e = __expf(2.f * x);
  return (e - 1.f) / (e + 1.f);
}

// ---------------- prep kernels ----------------
__global__ __launch_bounds__(256) void k_cvt(const float* __restrict__ whh,
                                             const float* __restrict__ linw,
                                             unsigned short* __restrict__ whhb,
                                             unsigned short* __restrict__ linwb) {
  int i = blockIdx.x * 256 + threadIdx.x;          // grid covers 2048*512 exactly
  whhb[i] = f2bf(whh[i]);
  if (i < OD * HD) linwb[i] = f2bf(linw[i]);
}

__global__ __launch_bounds__(256) void k_td(const float* __restrict__ t,
                                            float* __restrict__ td) {
  int i = blockIdx.x * 256 + threadIdx.x;          // SD*BD
  float v = 0.f;
  if (i >= BD) v = t[i] - t[i - BD];
  td[i] = v;
}

__global__ __launch_bounds__(256) void k_u(const float* __restrict__ wih,
                                           const float* __restrict__ tw,
                                           float* __restrict__ u) {
  int gc = blockIdx.x * 256 + threadIdx.x;         // 2048
  const float4* w4 = (const float4*)(wih + (size_t)gc * (2 * HD) + HD);
  const float4* t4 = (const float4*)tw;
  float a = 0.f;
  for (int k = 0; k < HD / 4; ++k) {
    float4 w = w4[k], tv = t4[k];
    a += w.x * tv.x + w.y * tv.y + w.z * tv.z + w.w * tv.w;
  }
  u[gc] = a;
}

__global__ __launch_bounds__(1024) void k_cw(const float* __restrict__ C,
                                             const float* __restrict__ wih,
                                             const float* __restrict__ bih,
                                             const float* __restrict__ bhh,
                                             const float* __restrict__ tb,
                                             float* __restrict__ CW) {
  int gc = blockIdx.x * 64 + (threadIdx.x & 63);
  int b  = blockIdx.y * 16 + (threadIdx.x >> 6);
  const float4* c4  = (const float4*)(C + (size_t)b * HD);
  const float4* w4  = (const float4*)(wih + (size_t)gc * (2 * HD));
  const float4* wt4 = (const float4*)(wih + (size_t)gc * (2 * HD) + HD);
  const float4* tb4 = (const float4*)tb;
  float acc = 0.f, acc2 = 0.f;
  for (int k = 0; k < HD / 4; ++k) {
    float4 cv = c4[k], wv = w4[k];
    acc += cv.x * wv.x + cv.y * wv.y + cv.z * wv.z + cv.w * wv.w;
    float4 tv = tb4[k], wt = wt4[k];
    acc2 += tv.x * wt.x + tv.y * wt.y + tv.z * wt.z + tv.w * wt.w;
  }
  CW[(size_t)b * (4 * HD) + gc] = acc + acc2 + bih[gc] + bhh[gc];
}

// ---------------- main recurrent kernel ----------------
__global__ __launch_bounds__(256, 1) void k_main(
    const float* __restrict__ CW, const float* __restrict__ u,
    const float* __restrict__ tdg, const unsigned short* __restrict__ whhb,
    const unsigned short* __restrict__ linwb, const float* __restrict__ linb,
    unsigned short* __restrict__ hbuf, unsigned int* __restrict__ ctr,
    float* __restrict__ out)
{
  __shared__ __align__(16) unsigned short Wlds[128 * HD]; // 128KB, swizzled
  __shared__ __align__(16) unsigned short hlds[16 * HD];  // 16KB, swizzled
  __shared__ float gbuf[4][16][32];                       // 8KB

  const int tid  = threadIdx.x;
  const int lane = tid & 63;
  const int wv   = tid >> 6;          // wave 0..3 == gate type i,f,g,o
  const int bid  = blockIdx.x;
  const int gid  = bid & 15;          // batch group (stride-16 members => same XCD)
  const int m    = bid >> 4;          // member: owns h-cols [m*32, m*32+32)

  // --- stage W_hh slice into LDS (rows g*512 + m*32 + jl), XOR-swizzled 16B chunks ---
  for (int i = tid; i < 128 * 64; i += 256) {
    int rl = i >> 6, c = i & 63;
    int gr = ((rl >> 5) * HD) + m * 32 + (rl & 31);
    int cs = c ^ (rl & 7);
    *(short8*)((char*)Wlds + (size_t)rl * 1024 + (size_t)c * 16) =
        *(const short8*)((const char*)whhb + (size_t)gr * 1024 + (size_t)cs * 16);
  }

  // --- step-invariant per-thread state (cell update mapping: (r, jl0), (r, jl0+1)) ---
  const int r    = tid >> 4;
  const int jl0  = (tid & 15) * 2;
  const int grow = gid * 16 + r;
  float cwr[8], ur[8];
  #pragma unroll
  for (int g = 0; g < 4; ++g) {
    int col = g * HD + m * 32 + jl0;
    cwr[g * 2]     = CW[(size_t)grow * (4 * HD) + col];
    cwr[g * 2 + 1] = CW[(size_t)grow * (4 * HD) + col + 1];
    ur[g * 2]      = u[col];
    ur[g * 2 + 1]  = u[col + 1];
  }
  float c0 = 0.f, c1 = 0.f;

  float lb = 0.f;
  const char* lwbase = nullptr;
  if (m < 8) {
    int oc = m * 16 + (lane & 15);
    lb = linb[oc];
    lwbase = (const char*)linwb + (size_t)oc * 1024;
  }

  short8 afrag[16];
  {
    short8 z = {0, 0, 0, 0, 0, 0, 0, 0};
    #pragma unroll
    for (int kk = 0; kk < 16; ++kk) afrag[kk] = z;   // h_0 = 0
  }

  unsigned int* myctr = ctr + gid * (SD + 1);
  unsigned short* hb  = hbuf + (size_t)gid * (2 * 16 * HD);

  const int row0 = wv * 32 + (lane & 15);
  const int row1 = row0 + 16;
  const int sw0  = (row0 & 7) << 4;
  const int sw1  = (row1 & 7) << 4;
  const int koff = (lane >> 4) * 16;
  const int arow = lane & 15;
  const int asw  = (arow & 7) << 4;

  __syncthreads();

  for (int t = 0; t < SD; ++t) {
    // ---- gates = h_t @ Whh_slice^T (wave wv: gate type wv, 32 cols) ----
    f32x4 acc0 = {0.f, 0.f, 0.f, 0.f}, acc1 = {0.f, 0.f, 0.f, 0.f};
    #pragma unroll
    for (int kk = 0; kk < 16; ++kk) {
      int kb = kk * 64 + koff;
      short8 b0 = *(const short8*)((const char*)Wlds + (size_t)row0 * 1024 + (kb ^ sw0));
      short8 b1 = *(const short8*)((const char*)Wlds + (size_t)row1 * 1024 + (kb ^ sw1));
      acc0 = __builtin_amdgcn_mfma_f32_16x16x32_bf16(afrag[kk], b0, acc0, 0, 0, 0);
      acc1 = __builtin_amdgcn_mfma_f32_16x16x32_bf16(afrag[kk], b1, acc1, 0, 0, 0);
    }
    {
      int rr = (lane >> 4) * 4, cc = lane & 15;
      #pragma unroll
      for (int q = 0; q < 4; ++q) {
        gbuf[wv][rr + q][cc]      = acc0[q];
        gbuf[wv][rr + q][16 + cc] = acc1[q];
      }
    }
    __syncthreads();  // B1: gates visible

    // ---- LSTM cell update for 2 elements ----
    {
      float tdv = tdg[t * BD + grow];
      float p0i = gbuf[0][r][jl0]     + cwr[0] + tdv * ur[0];
      float p1i = gbuf[0][r][jl0 + 1] + cwr[1] + tdv * ur[1];
      float p0f = gbuf[1][r][jl0]     + cwr[2] + tdv * ur[2];
      float p1f = gbuf[1][r][jl0 + 1] + cwr[3] + tdv * ur[3];
      float p0g = gbuf[2][r][jl0]     + cwr[4] + tdv * ur[4];
      float p1g = gbuf[2][r][jl0 + 1] + cwr[5] + tdv * ur[5];
      float p0o = gbuf[3][r][jl0]     + cwr[6] + tdv * ur[6];
      float p1o = gbuf[3][r][jl0 + 1] + cwr[7] + tdv * ur[7];
      c0 = sigm(p0f) * c0 + sigm(p0i) * tanhf_(p0g);
      c1 = sigm(p1f) * c1 + sigm(p1i) * tanhf_(p1g);
      float h0 = sigm(p0o) * tanhf_(c0);
      float h1 = sigm(p1o) * tanhf_(c1);
      unsigned int hp = (unsigned int)f2bf(h0) | ((unsigned int)f2bf(h1) << 16);
      int par = (t + 1) & 1;
      *(unsigned int*)(hb + (size_t)par * (16 * HD) + (size_t)r * HD + m * 32 + jl0) = hp;
    }
    __threadfence();
    __syncthreads();  // B2: all wg stores fenced
    if (tid == 0) {
      __hip_atomic_fetch_add(&myctr[t + 1], 1u, __ATOMIC_RELEASE, __HIP_MEMORY_SCOPE_AGENT);
      int it = 0;
      while (__hip_atomic_load(&myctr[t + 1], __ATOMIC_RELAXED, __HIP_MEMORY_SCOPE_AGENT) < 16u) {
        if (++it > 200000) break;  // bounded: garbage-not-hang on residency failure
      }
    }
    __syncthreads();  // B3
    __threadfence();  // acquire: invalidate L1 before reading peers' h

    // ---- load full h_{t+1} into LDS (swizzled source chunks) ----
    {
      int par = (t + 1) & 1;
      const char* src = (const char*)(hb + (size_t)par * (16 * HD));
      #pragma unroll
      for (int it2 = 0; it2 < 4; ++it2) {
        int i2 = tid + it2 * 256;
        int rr = i2 >> 6, c = i2 & 63;
        int cs = c ^ (rr & 7);
        *(short8*)((char*)hlds + (size_t)rr * 1024 + (size_t)c * 16) =
            *(const short8*)(src + (size_t)rr * 1024 + (size_t)cs * 16);
      }
    }
    __syncthreads();  // B4: hlds ready

    // ---- refresh A-frags (h_{t+1}) ----
    #pragma unroll
    for (int kk = 0; kk < 16; ++kk) {
      int kb = kk * 64 + koff;
      afrag[kk] = *(const short8*)((const char*)hlds + (size_t)arow * 1024 + (kb ^ asw));
    }

    // ---- out[t] = h_{t+1} @ lin_W^T + lin_b (wgs m<8, 16 out-cols each) ----
    if (m < 8) {
      f32x4 osum = {0.f, 0.f, 0.f, 0.f};
      #pragma unroll
      for (int kk = 0; kk < 16; ++kk) {
        short8 bf = *(const short8*)(lwbase + kk * 64 + koff);
        osum = __builtin_amdgcn_mfma_f32_16x16x32_bf16(afrag[kk], bf, osum, 0, 0, 0);
      }
      float* ob = out + (size_t)t * (BD * OD) + (size_t)(gid * 16) * OD + m * 16;
      int rr = (lane >> 4) * 4, cc = lane & 15;
      #pragma unroll
      for (int q = 0; q < 4; ++q)
        ob[(size_t)(rr + q) * OD + cc] = osum[q] + lb;
    }
  }
}

// ---------------- launcher ----------------
extern "C" void kernel_launch(void* const* d_in, const int* in_sizes, int n_in,
                              void* d_out, int out_size, void* d_ws, size_t ws_size,
                              hipStream_t stream) {
  const float* C    = (const float*)d_in[0];
  const float* t    = (const float*)d_in[1];
  // d_in[2] = mask (unused by reference)
  const float* Wih  = (const float*)d_in[3];
  const float* Whh  = (const float*)d_in[4];
  const float* bih  = (const float*)d_in[5];
  const float* bhh  = (const float*)d_in[6];
  const float* linW = (const float*)d_in[7];
  const float* linb = (const float*)d_in[8];
  const float* tW   = (const float*)d_in[9];
  const float* tb   = (const float*)d_in[10];
  float* out = (float*)d_out;

  // ws layout (all 256B-aligned)
  char* ws = (char*)d_ws;
  float*          CW    = (float*)(ws + 0);                 // 256*2048*4   = 2,097,152
  float*          u     = (float*)(ws + 2097152);           // 2048*4       = 8,192
  float*          td    = (float*)(ws + 2105344);           // 512*256*4    = 524,288
  unsigned short* whhb  = (unsigned short*)(ws + 2629632);  // 2048*512*2   = 2,097,152
  unsigned short* linwb = (unsigned short*)(ws + 4726784);  // 128*512*2    = 131,072
  unsigned short* hbuf  = (unsigned short*)(ws + 4857856);  // 16*2*16*512*2= 524,288
  unsigned int*   ctr   = (unsigned int*)(ws + 5382144);    // 16*513*4     = 32,832
  if (ws_size < 5414976) return;  // fail visibly (poisoned out) rather than corrupt

  hipMemsetAsync(ctr, 0, 16 * (SD + 1) * 4, stream);
  k_cvt<<<4096, 256, 0, stream>>>(Whh, linW, whhb, linwb);
  k_td <<<512, 256, 0, stream>>>(t, td);
  k_u  <<<8, 256, 0, stream>>>(Wih, tW, u);
  k_cw <<<dim3(32, 16), 1024, 0, stream>>>(C, Wih, bih, bhh, tb, CW);
  k_main<<<256, 256, 0, stream>>>(CW, u, td, whhb, linwb, linb, hbuf, ctr, out);
}

// Round 2
// 3357.503 us; speedup vs baseline: 5.8729x; 5.8729x over previous
//
#include <hip/hip_runtime.h>
#include <stdint.h>

// LSTMTimeDecoder on MI355X — round 2.
// Same decomposition as round 1; the cross-wg h-exchange is now FENCE-FREE:
// all cross-wg data uses device-coherent (sc0 sc1 / agent-scope relaxed)
// load/store, ordering via explicit s_waitcnt vmcnt(0). No __threadfence
// (which emitted buffer_wbl2 = full 4MiB L2 writeback per step — the 39us/step
// cost in round 1). Per-wave flag adds (target 64/group) make the spin double
// as the intra-wg barrier.

#define HD 512
#define BD 256
#define SD 512
#define OD 128

typedef __attribute__((ext_vector_type(8))) short short8;
typedef __attribute__((ext_vector_type(4))) float f32x4;

static __device__ __forceinline__ unsigned short f2bf(float x) {
  unsigned int u = __float_as_uint(x);
  u += 0x7fffu + ((u >> 16) & 1u);
  return (unsigned short)(u >> 16);
}
static __device__ __forceinline__ float sigm(float x) {
  return 1.0f / (1.0f + __expf(-x));
}
static __device__ __forceinline__ float tanhf_(float x) {
  x = fminf(15.f, fmaxf(-15.f, x));
  float e = __expf(2.f * x);
  return (e - 1.f) / (e + 1.f);
}

// ---------------- prep kernels (unchanged, verified round 1) ----------------
__global__ __launch_bounds__(256) void k_cvt(const float* __restrict__ whh,
                                             const float* __restrict__ linw,
                                             unsigned short* __restrict__ whhb,
                                             unsigned short* __restrict__ linwb) {
  int i = blockIdx.x * 256 + threadIdx.x;
  whhb[i] = f2bf(whh[i]);
  if (i < OD * HD) linwb[i] = f2bf(linw[i]);
}

__global__ __launch_bounds__(256) void k_td(const float* __restrict__ t,
                                            float* __restrict__ td) {
  int i = blockIdx.x * 256 + threadIdx.x;
  float v = 0.f;
  if (i >= BD) v = t[i] - t[i - BD];
  td[i] = v;
}

__global__ __launch_bounds__(256) void k_u(const float* __restrict__ wih,
                                           const float* __restrict__ tw,
                                           float* __restrict__ u) {
  int gc = blockIdx.x * 256 + threadIdx.x;
  const float4* w4 = (const float4*)(wih + (size_t)gc * (2 * HD) + HD);
  const float4* t4 = (const float4*)tw;
  float a = 0.f;
  for (int k = 0; k < HD / 4; ++k) {
    float4 w = w4[k], tv = t4[k];
    a += w.x * tv.x + w.y * tv.y + w.z * tv.z + w.w * tv.w;
  }
  u[gc] = a;
}

__global__ __launch_bounds__(1024) void k_cw(const float* __restrict__ C,
                                             const float* __restrict__ wih,
                                             const float* __restrict__ bih,
                                             const float* __restrict__ bhh,
                                             const float* __restrict__ tb,
                                             float* __restrict__ CW) {
  int gc = blockIdx.x * 64 + (threadIdx.x & 63);
  int b  = blockIdx.y * 16 + (threadIdx.x >> 6);
  const float4* c4  = (const float4*)(C + (size_t)b * HD);
  const float4* w4  = (const float4*)(wih + (size_t)gc * (2 * HD));
  const float4* wt4 = (const float4*)(wih + (size_t)gc * (2 * HD) + HD);
  const float4* tb4 = (const float4*)tb;
  float acc = 0.f, acc2 = 0.f;
  for (int k = 0; k < HD / 4; ++k) {
    float4 cv = c4[k], wv = w4[k];
    acc += cv.x * wv.x + cv.y * wv.y + cv.z * wv.z + cv.w * wv.w;
    float4 tv = tb4[k], wt = wt4[k];
    acc2 += tv.x * wt.x + tv.y * wt.y + tv.z * wt.z + tv.w * wt.w;
  }
  CW[(size_t)b * (4 * HD) + gc] = acc + acc2 + bih[gc] + bhh[gc];
}

// ---------------- main recurrent kernel ----------------
__global__ __launch_bounds__(256, 1) void k_main(
    const float* __restrict__ CW, const float* __restrict__ u,
    const float* __restrict__ tdg, const unsigned short* __restrict__ whhb,
    const unsigned short* __restrict__ linwb, const float* __restrict__ linb,
    unsigned short* __restrict__ hbuf, unsigned int* __restrict__ ctr,
    float* __restrict__ out)
{
  __shared__ __align__(16) unsigned short Wlds[128 * HD]; // 128KB, swizzled
  __shared__ __align__(16) unsigned short hlds[16 * HD];  // 16KB, swizzled
  __shared__ float gbuf[4][16][33];                       // padded: 2-way max

  const int tid  = threadIdx.x;
  const int lane = tid & 63;
  const int wv   = tid >> 6;          // wave 0..3 == gate type i,f,g,o
  const int gid  = blockIdx.x & 15;   // batch group
  const int m    = blockIdx.x >> 4;   // member: owns h-cols [m*32, m*32+32)

  // --- stage W_hh slice into LDS (XOR-swizzled 16B chunks) ---
  for (int i = tid; i < 128 * 64; i += 256) {
    int rl = i >> 6, c = i & 63;
    int gr = ((rl >> 5) * HD) + m * 32 + (rl & 31);
    int cs = c ^ (rl & 7);
    *(short8*)((char*)Wlds + (size_t)rl * 1024 + (size_t)c * 16) =
        *(const short8*)((const char*)whhb + (size_t)gr * 1024 + (size_t)cs * 16);
  }

  // --- step-invariant per-thread state ---
  const int r    = tid >> 4;
  const int jl0  = (tid & 15) * 2;
  const int grow = gid * 16 + r;
  float cwr[8], ur[8];
  #pragma unroll
  for (int g = 0; g < 4; ++g) {
    int col = g * HD + m * 32 + jl0;
    cwr[g * 2]     = CW[(size_t)grow * (4 * HD) + col];
    cwr[g * 2 + 1] = CW[(size_t)grow * (4 * HD) + col + 1];
    ur[g * 2]      = u[col];
    ur[g * 2 + 1]  = u[col + 1];
  }
  float c0 = 0.f, c1 = 0.f;

  float lb = 0.f;
  const char* lwbase = nullptr;
  if (m < 8) {
    int oc = m * 16 + (lane & 15);
    lb = linb[oc];
    lwbase = (const char*)linwb + (size_t)oc * 1024;
  }

  short8 afrag[16];
  {
    short8 z = {0, 0, 0, 0, 0, 0, 0, 0};
    #pragma unroll
    for (int kk = 0; kk < 16; ++kk) afrag[kk] = z;   // h_0 = 0
  }

  unsigned int* myctr = ctr + gid * (SD + 1);
  unsigned short* hb  = hbuf + (size_t)gid * (2 * 16 * HD);

  const int row0 = wv * 32 + (lane & 15);
  const int row1 = row0 + 16;
  const int sw0  = (row0 & 7) << 4;
  const int sw1  = (row1 & 7) << 4;
  const int koff = (lane >> 4) * 16;
  const int arow = lane & 15;
  const int asw  = (arow & 7) << 4;

  float tdv = tdg[grow];   // step 0 (==0 by construction)

  __syncthreads();

  for (int t = 0; t < SD; ++t) {
    // ---- gates = h_t @ Whh_slice^T ----
    f32x4 acc0 = {0.f, 0.f, 0.f, 0.f}, acc1 = {0.f, 0.f, 0.f, 0.f};
    #pragma unroll
    for (int kk = 0; kk < 16; ++kk) {
      int kb = kk * 64 + koff;
      short8 b0 = *(const short8*)((const char*)Wlds + (size_t)row0 * 1024 + (kb ^ sw0));
      short8 b1 = *(const short8*)((const char*)Wlds + (size_t)row1 * 1024 + (kb ^ sw1));
      acc0 = __builtin_amdgcn_mfma_f32_16x16x32_bf16(afrag[kk], b0, acc0, 0, 0, 0);
      acc1 = __builtin_amdgcn_mfma_f32_16x16x32_bf16(afrag[kk], b1, acc1, 0, 0, 0);
    }
    {
      int rr = (lane >> 4) * 4, cc = lane & 15;
      #pragma unroll
      for (int q = 0; q < 4; ++q) {
        gbuf[wv][rr + q][cc]      = acc0[q];
        gbuf[wv][rr + q][16 + cc] = acc1[q];
      }
    }
    __syncthreads();  // B1: gates visible in gbuf

    // ---- output projection for row t-1 (afrag still = h_t); MFMA pipe
    //      overlaps the cell's VALU work below ----
    if (m < 8 && t > 0) {
      f32x4 osum = {0.f, 0.f, 0.f, 0.f};
      #pragma unroll
      for (int kk = 0; kk < 16; ++kk) {
        short8 bf = *(const short8*)(lwbase + kk * 64 + koff);
        osum = __builtin_amdgcn_mfma_f32_16x16x32_bf16(afrag[kk], bf, osum, 0, 0, 0);
      }
      float* ob = out + (size_t)(t - 1) * (BD * OD) + (size_t)(gid * 16) * OD + m * 16;
      int rr = (lane >> 4) * 4, cc = lane & 15;
      #pragma unroll
      for (int q = 0; q < 4; ++q)
        ob[(size_t)(rr + q) * OD + cc] = osum[q] + lb;
    }

    // ---- LSTM cell update (2 elements/thread) ----
    const int par = (t + 1) & 1;
    {
      float p0i = gbuf[0][r][jl0]     + cwr[0] + tdv * ur[0];
      float p1i = gbuf[0][r][jl0 + 1] + cwr[1] + tdv * ur[1];
      float p0f = gbuf[1][r][jl0]     + cwr[2] + tdv * ur[2];
      float p1f = gbuf[1][r][jl0 + 1] + cwr[3] + tdv * ur[3];
      float p0g = gbuf[2][r][jl0]     + cwr[4] + tdv * ur[4];
      float p1g = gbuf[2][r][jl0 + 1] + cwr[5] + tdv * ur[5];
      float p0o = gbuf[3][r][jl0]     + cwr[6] + tdv * ur[6];
      float p1o = gbuf[3][r][jl0 + 1] + cwr[7] + tdv * ur[7];
      c0 = sigm(p0f) * c0 + sigm(p0i) * tanhf_(p0g);
      c1 = sigm(p1f) * c1 + sigm(p1i) * tanhf_(p1g);
      float h0 = sigm(p0o) * tanhf_(c0);
      float h1 = sigm(p1o) * tanhf_(c1);
      unsigned int hp = (unsigned int)f2bf(h0) | ((unsigned int)f2bf(h1) << 16);
      unsigned int* hslot = (unsigned int*)(hb + (size_t)par * (16 * HD) +
                                            (size_t)r * HD + m * 32 + jl0);
      // device-coherent write-through store (sc1): no fence needed
      __hip_atomic_store(hslot, hp, __ATOMIC_RELAXED, __HIP_MEMORY_SCOPE_AGENT);
    }
    // drain this wave's write-through stores to the coherence point,
    // then signal arrival. RELAXED => no buffer_wbl2 / buffer_inv.
    asm volatile("s_waitcnt vmcnt(0)" ::: "memory");
    if (lane == 0)
      __hip_atomic_fetch_add(&myctr[t + 1], 1u, __ATOMIC_RELAXED, __HIP_MEMORY_SCOPE_AGENT);

    if (t + 1 < SD) tdv = tdg[(size_t)(t + 1) * BD + grow];  // hide under spin

    // ---- spin: 64 wave-arrivals == all h_{t+1} slices at coherence point.
    //      Doubles as the cross-wave barrier for gbuf/hlds reuse. ----
    {
      int guard = 0;
      while (__hip_atomic_load(&myctr[t + 1], __ATOMIC_RELAXED,
                               __HIP_MEMORY_SCOPE_AGENT) < 64u) {
        if (++guard > (1 << 22)) break;  // bounded: garbage-not-hang
      }
    }

    // ---- reload full h_{t+1}: device-coherent loads -> LDS (swizzled) ----
    {
      const char* src = (const char*)hb + (size_t)par * 16384 + (size_t)tid * 16;
      short8 v0, v1, v2, v3;
      asm volatile("global_load_dwordx4 %0, %1, off sc0 sc1" : "=v"(v0) : "v"(src) : "memory");
      asm volatile("global_load_dwordx4 %0, %1, off sc0 sc1" : "=v"(v1) : "v"(src + 4096) : "memory");
      asm volatile("global_load_dwordx4 %0, %1, off sc0 sc1" : "=v"(v2) : "v"(src + 8192) : "memory");
      asm volatile("global_load_dwordx4 %0, %1, off sc0 sc1" : "=v"(v3) : "v"(src + 12288) : "memory");
      asm volatile("s_waitcnt vmcnt(0)" ::: "memory");
      __builtin_amdgcn_sched_barrier(0);
      const int c = tid & 63;
      {
        int rr = wv;
        *(short8*)((char*)hlds + (size_t)rr * 1024 + (size_t)((c ^ (rr & 7)) * 16)) = v0;
      }
      {
        int rr = wv + 4;
        *(short8*)((char*)hlds + (size_t)rr * 1024 + (size_t)((c ^ (rr & 7)) * 16)) = v1;
      }
      {
        int rr = wv + 8;
        *(short8*)((char*)hlds + (size_t)rr * 1024 + (size_t)((c ^ (rr & 7)) * 16)) = v2;
      }
      {
        int rr = wv + 12;
        *(short8*)((char*)hlds + (size_t)rr * 1024 + (size_t)((c ^ (rr & 7)) * 16)) = v3;
      }
    }
    __syncthreads();  // B2: hlds ready

    // ---- refresh A-frags (h_{t+1}) ----
    #pragma unroll
    for (int kk = 0; kk < 16; ++kk) {
      int kb = kk * 64 + koff;
      afrag[kk] = *(const short8*)((const char*)hlds + (size_t)arow * 1024 + (kb ^ asw));
    }
  }

  // ---- tail: out row SD-1 (afrag = h_SD) ----
  if (m < 8) {
    f32x4 osum = {0.f, 0.f, 0.f, 0.f};
    #pragma unroll
    for (int kk = 0; kk < 16; ++kk) {
      short8 bf = *(const short8*)(lwbase + kk * 64 + koff);
      osum = __builtin_amdgcn_mfma_f32_16x16x32_bf16(afrag[kk], bf, osum, 0, 0, 0);
    }
    float* ob = out + (size_t)(SD - 1) * (BD * OD) + (size_t)(gid * 16) * OD + m * 16;
    int rr = (lane >> 4) * 4, cc = lane & 15;
    #pragma unroll
    for (int q = 0; q < 4; ++q)
      ob[(size_t)(rr + q) * OD + cc] = osum[q] + lb;
  }
}

// ---------------- launcher ----------------
extern "C" void kernel_launch(void* const* d_in, const int* in_sizes, int n_in,
                              void* d_out, int out_size, void* d_ws, size_t ws_size,
                              hipStream_t stream) {
  const float* C    = (const float*)d_in[0];
  const float* t    = (const float*)d_in[1];
  // d_in[2] = mask (unused by reference)
  const float* Wih  = (const float*)d_in[3];
  const float* Whh  = (const float*)d_in[4];
  const float* bih  = (const float*)d_in[5];
  const float* bhh  = (const float*)d_in[6];
  const float* linW = (const float*)d_in[7];
  const float* linb = (const float*)d_in[8];
  const float* tW   = (const float*)d_in[9];
  const float* tb   = (const float*)d_in[10];
  float* out = (float*)d_out;

  char* ws = (char*)d_ws;
  float*          CW    = (float*)(ws + 0);                 // 2,097,152
  float*          u     = (float*)(ws + 2097152);           // 8,192
  float*          td    = (float*)(ws + 2105344);           // 524,288
  unsigned short* whhb  = (unsigned short*)(ws + 2629632);  // 2,097,152
  unsigned short* linwb = (unsigned short*)(ws + 4726784);  // 131,072
  unsigned short* hbuf  = (unsigned short*)(ws + 4857856);  // 524,288
  unsigned int*   ctr   = (unsigned int*)(ws + 5382144);    // 32,832
  if (ws_size < 5414976) return;

  hipMemsetAsync(ctr, 0, 16 * (SD + 1) * 4, stream);
  k_cvt<<<4096, 256, 0, stream>>>(Whh, linW, whhb, linwb);
  k_td <<<512, 256, 0, stream>>>(t, td);
  k_u  <<<8, 256, 0, stream>>>(Wih, tW, u);
  k_cw <<<dim3(32, 16), 1024, 0, stream>>>(C, Wih, bih, bhh, tb, CW);
  k_main<<<256, 256, 0, stream>>>(CW, u, td, whhb, linwb, linb, hbuf, ctr, out);
}

// Round 3
// 2294.149 us; speedup vs baseline: 8.5950x; 1.4635x over previous
//
#include <hip/hip_runtime.h>
#include <stdint.h>

// LSTMTimeDecoder on MI355X — round 3.
// Exchange redesign vs round 2: NO atomics. Per-WAVE flag words written with
// plain device-coherent stores (sc0 sc1) after a per-wave vmcnt(0) drain of its
// h-slice stores; wave 0 polls all 64 group flags with one coalesced gather
// (__all(fv >= t+1), monotone so no reset races). Output projection deduped to
// one wave and moved into the poll window. Round 2's cost was 64 serialized
// atomic RMWs/step on one L3 line + full-wg rendezvous before signaling.

#define HD 512
#define BD 256
#define SD 512
#define OD 128

typedef __attribute__((ext_vector_type(8))) short short8;
typedef __attribute__((ext_vector_type(4))) float f32x4;

static __device__ __forceinline__ unsigned short f2bf(float x) {
  unsigned int u = __float_as_uint(x);
  u += 0x7fffu + ((u >> 16) & 1u);
  return (unsigned short)(u >> 16);
}
static __device__ __forceinline__ float sigm(float x) {
  return 1.0f / (1.0f + __expf(-x));
}
static __device__ __forceinline__ float tanhf_(float x) {
  x = fminf(15.f, fmaxf(-15.f, x));
  float e = __expf(2.f * x);
  return (e - 1.f) / (e + 1.f);
}

// ---------------- prep kernels ----------------
__global__ __launch_bounds__(256) void k_cvt(const float* __restrict__ whh,
                                             const float* __restrict__ linw,
                                             unsigned short* __restrict__ whhb,
                                             unsigned short* __restrict__ linwb) {
  int i = blockIdx.x * 256 + threadIdx.x;
  whhb[i] = f2bf(whh[i]);
  if (i < OD * HD) linwb[i] = f2bf(linw[i]);
}

__global__ __launch_bounds__(256) void k_td(const float* __restrict__ t,
                                            float* __restrict__ td) {
  int i = blockIdx.x * 256 + threadIdx.x;
  float v = 0.f;
  if (i >= BD) v = t[i] - t[i - BD];
  td[i] = v;
}

// u[gc] = W_ih[gc, H:] . time_W ;  ub[gc] = W_ih[gc, H:] . time_b + b_ih + b_hh
__global__ __launch_bounds__(256) void k_u(const float* __restrict__ wih,
                                           const float* __restrict__ tw,
                                           const float* __restrict__ tb,
                                           const float* __restrict__ bih,
                                           const float* __restrict__ bhh,
                                           float* __restrict__ u,
                                           float* __restrict__ ub) {
  int gc = blockIdx.x * 256 + threadIdx.x;
  const float4* w4 = (const float4*)(wih + (size_t)gc * (2 * HD) + HD);
  const float4* t4 = (const float4*)tw;
  const float4* b4 = (const float4*)tb;
  float a = 0.f, b = 0.f;
  for (int k = 0; k < HD / 4; ++k) {
    float4 w = w4[k], tv = t4[k], bv = b4[k];
    a += w.x * tv.x + w.y * tv.y + w.z * tv.z + w.w * tv.w;
    b += w.x * bv.x + w.y * bv.y + w.z * bv.z + w.w * bv.w;
  }
  u[gc] = a;
  ub[gc] = b + bih[gc] + bhh[gc];
}

__global__ __launch_bounds__(1024) void k_cw(const float* __restrict__ C,
                                             const float* __restrict__ wih,
                                             const float* __restrict__ ub,
                                             float* __restrict__ CW) {
  int gc = blockIdx.x * 64 + (threadIdx.x & 63);
  int b  = blockIdx.y * 16 + (threadIdx.x >> 6);
  const float4* c4 = (const float4*)(C + (size_t)b * HD);
  const float4* w4 = (const float4*)(wih + (size_t)gc * (2 * HD));
  float acc = 0.f;
  for (int k = 0; k < HD / 4; ++k) {
    float4 cv = c4[k], wv = w4[k];
    acc += cv.x * wv.x + cv.y * wv.y + cv.z * wv.z + cv.w * wv.w;
  }
  CW[(size_t)b * (4 * HD) + gc] = acc + ub[gc];
}

// ---------------- main recurrent kernel ----------------
__global__ __launch_bounds__(256, 1) void k_main(
    const float* __restrict__ CW, const float* __restrict__ u,
    const float* __restrict__ tdg, const unsigned short* __restrict__ whhb,
    const unsigned short* __restrict__ linwb, const float* __restrict__ linb,
    unsigned short* __restrict__ hbuf, unsigned int* __restrict__ flagw,
    float* __restrict__ out)
{
  __shared__ __align__(16) unsigned short Wlds[128 * HD]; // 128KB, swizzled
  __shared__ __align__(16) unsigned short hlds[16 * HD];  // 16KB, swizzled
  __shared__ float gbuf[4][16][33];

  const int tid  = threadIdx.x;
  const int lane = tid & 63;
  const int wv   = tid >> 6;          // wave 0..3 == gate type i,f,g,o
  const int gid  = blockIdx.x & 15;   // batch group
  const int m    = blockIdx.x >> 4;   // member: owns h-cols [m*32, m*32+32)

  // --- stage W_hh slice into LDS (XOR-swizzled 16B chunks) ---
  for (int i = tid; i < 128 * 64; i += 256) {
    int rl = i >> 6, c = i & 63;
    int gr = ((rl >> 5) * HD) + m * 32 + (rl & 31);
    int cs = c ^ (rl & 7);
    *(short8*)((char*)Wlds + (size_t)rl * 1024 + (size_t)c * 16) =
        *(const short8*)((const char*)whhb + (size_t)gr * 1024 + (size_t)cs * 16);
  }

  // --- step-invariant per-thread state ---
  const int r    = tid >> 4;
  const int jl0  = (tid & 15) * 2;
  const int grow = gid * 16 + r;
  float cwr[8], ur[8];
  #pragma unroll
  for (int g = 0; g < 4; ++g) {
    int col = g * HD + m * 32 + jl0;
    cwr[g * 2]     = CW[(size_t)grow * (4 * HD) + col];
    cwr[g * 2 + 1] = CW[(size_t)grow * (4 * HD) + col + 1];
    ur[g * 2]      = u[col];
    ur[g * 2 + 1]  = u[col + 1];
  }
  float c0 = 0.f, c1 = 0.f;

  const int wsel = 1 + (m % 3);       // designated out-projection wave (1..3)
  float lb = 0.f;
  const char* lwbase = nullptr;
  if (m < 8) {
    int oc = m * 16 + (lane & 15);
    lb = linb[oc];
    lwbase = (const char*)linwb + (size_t)oc * 1024;
  }

  short8 afrag[16];
  {
    short8 z = {0, 0, 0, 0, 0, 0, 0, 0};
    #pragma unroll
    for (int kk = 0; kk < 16; ++kk) afrag[kk] = z;   // h_0 = 0
  }

  unsigned int*   fbase = flagw + gid * 64;
  unsigned short* hb    = hbuf + (size_t)gid * (2 * 16 * HD);

  const int row0 = wv * 32 + (lane & 15);
  const int row1 = row0 + 16;
  const int sw0  = (row0 & 7) << 4;
  const int sw1  = (row1 & 7) << 4;
  const int koff = (lane >> 4) * 16;
  const int arow = lane & 15;
  const int asw  = (arow & 7) << 4;

  float tdv = tdg[grow];   // step 0 (==0 by construction)

  __syncthreads();

  for (int t = 0; t < SD; ++t) {
    // ---- gates = h_t @ Whh_slice^T ----
    f32x4 acc0 = {0.f, 0.f, 0.f, 0.f}, acc1 = {0.f, 0.f, 0.f, 0.f};
    #pragma unroll
    for (int kk = 0; kk < 16; ++kk) {
      int kb = kk * 64 + koff;
      short8 b0 = *(const short8*)((const char*)Wlds + (size_t)row0 * 1024 + (kb ^ sw0));
      short8 b1 = *(const short8*)((const char*)Wlds + (size_t)row1 * 1024 + (kb ^ sw1));
      acc0 = __builtin_amdgcn_mfma_f32_16x16x32_bf16(afrag[kk], b0, acc0, 0, 0, 0);
      acc1 = __builtin_amdgcn_mfma_f32_16x16x32_bf16(afrag[kk], b1, acc1, 0, 0, 0);
    }
    {
      int rr = (lane >> 4) * 4, cc = lane & 15;
      #pragma unroll
      for (int q = 0; q < 4; ++q) {
        gbuf[wv][rr + q][cc]      = acc0[q];
        gbuf[wv][rr + q][16 + cc] = acc1[q];
      }
    }
    __syncthreads();  // B1: gates visible in gbuf

    // ---- LSTM cell update (2 elements/thread) ----
    const int par = (t + 1) & 1;
    {
      float p0i = gbuf[0][r][jl0]     + cwr[0] + tdv * ur[0];
      float p1i = gbuf[0][r][jl0 + 1] + cwr[1] + tdv * ur[1];
      float p0f = gbuf[1][r][jl0]     + cwr[2] + tdv * ur[2];
      float p1f = gbuf[1][r][jl0 + 1] + cwr[3] + tdv * ur[3];
      float p0g = gbuf[2][r][jl0]     + cwr[4] + tdv * ur[4];
      float p1g = gbuf[2][r][jl0 + 1] + cwr[5] + tdv * ur[5];
      float p0o = gbuf[3][r][jl0]     + cwr[6] + tdv * ur[6];
      float p1o = gbuf[3][r][jl0 + 1] + cwr[7] + tdv * ur[7];
      c0 = sigm(p0f) * c0 + sigm(p0i) * tanhf_(p0g);
      c1 = sigm(p1f) * c1 + sigm(p1i) * tanhf_(p1g);
      float h0 = sigm(p0o) * tanhf_(c0);
      float h1 = sigm(p1o) * tanhf_(c1);
      unsigned int hp = (unsigned int)f2bf(h0) | ((unsigned int)f2bf(h1) << 16);
      unsigned int* hslot = (unsigned int*)(hb + (size_t)par * (16 * HD) +
                                            (size_t)r * HD + m * 32 + jl0);
      __hip_atomic_store(hslot, hp, __ATOMIC_RELAXED, __HIP_MEMORY_SCOPE_AGENT);
    }

    // ---- per-wave drain + flag store (plain coherent store, no RMW) ----
    asm volatile("s_waitcnt vmcnt(0)" ::: "memory");
    __builtin_amdgcn_sched_barrier(0);
    if (lane == 0) {
      unsigned int fv = (unsigned int)(t + 1);
      asm volatile("global_store_dword %0, %1, off sc0 sc1"
                   :: "v"(fbase + m * 4 + wv), "v"(fv) : "memory");
    }
    __builtin_amdgcn_sched_barrier(0);

    // prefetch next tdv (hides under poll / out-proj)
    if (t + 1 < SD) tdv = tdg[(size_t)(t + 1) * BD + grow];

    if (wv == 0) {
      // ---- poll: one coalesced gather of the 64 per-wave flags ----
      const unsigned int* fp = fbase + lane;
      int guard = 0;
      for (;;) {
        unsigned int fv;
        asm volatile("global_load_dword %0, %1, off sc0 sc1\n\ts_waitcnt vmcnt(0)"
                     : "=v"(fv) : "v"(fp) : "memory");
        if (__all(fv >= (unsigned int)(t + 1))) break;
        if (++guard > (1 << 16)) break;  // bounded: garbage-not-hang
      }
    } else if (wv == wsel && m < 8 && t > 0) {
      // ---- out row t-1 (afrag still = h_t); hides under wave0's poll ----
      f32x4 osum = {0.f, 0.f, 0.f, 0.f};
      #pragma unroll
      for (int kk = 0; kk < 16; ++kk) {
        short8 bf = *(const short8*)(lwbase + kk * 64 + koff);
        osum = __builtin_amdgcn_mfma_f32_16x16x32_bf16(afrag[kk], bf, osum, 0, 0, 0);
      }
      float* ob = out + (size_t)(t - 1) * (BD * OD) + (size_t)(gid * 16) * OD + m * 16;
      int rr = (lane >> 4) * 4, cc = lane & 15;
      #pragma unroll
      for (int q = 0; q < 4; ++q)
        ob[(size_t)(rr + q) * OD + cc] = osum[q] + lb;
    }
    __syncthreads();  // B3: exchange complete

    // ---- reload full h_{t+1}: device-coherent loads -> LDS (swizzled) ----
    {
      const char* src = (const char*)hb + (size_t)par * 16384 + (size_t)tid * 16;
      short8 v0, v1, v2, v3;
      asm volatile("global_load_dwordx4 %0, %1, off sc0 sc1" : "=v"(v0) : "v"(src) : "memory");
      asm volatile("global_load_dwordx4 %0, %1, off sc0 sc1" : "=v"(v1) : "v"(src + 4096) : "memory");
      asm volatile("global_load_dwordx4 %0, %1, off sc0 sc1" : "=v"(v2) : "v"(src + 8192) : "memory");
      asm volatile("global_load_dwordx4 %0, %1, off sc0 sc1" : "=v"(v3) : "v"(src + 12288) : "memory");
      asm volatile("s_waitcnt vmcnt(0)" ::: "memory");
      __builtin_amdgcn_sched_barrier(0);
      const int c = tid & 63;
      { int rr = wv;      *(short8*)((char*)hlds + (size_t)rr * 1024 + (size_t)((c ^ (rr & 7)) * 16)) = v0; }
      { int rr = wv + 4;  *(short8*)((char*)hlds + (size_t)rr * 1024 + (size_t)((c ^ (rr & 7)) * 16)) = v1; }
      { int rr = wv + 8;  *(short8*)((char*)hlds + (size_t)rr * 1024 + (size_t)((c ^ (rr & 7)) * 16)) = v2; }
      { int rr = wv + 12; *(short8*)((char*)hlds + (size_t)rr * 1024 + (size_t)((c ^ (rr & 7)) * 16)) = v3; }
    }
    __syncthreads();  // B4: hlds ready

    // ---- refresh A-frags (h_{t+1}) ----
    #pragma unroll
    for (int kk = 0; kk < 16; ++kk) {
      int kb = kk * 64 + koff;
      afrag[kk] = *(const short8*)((const char*)hlds + (size_t)arow * 1024 + (kb ^ asw));
    }
  }

  // ---- tail: out row SD-1 (afrag = h_SD) ----
  if (m < 8 && wv == wsel) {
    f32x4 osum = {0.f, 0.f, 0.f, 0.f};
    #pragma unroll
    for (int kk = 0; kk < 16; ++kk) {
      short8 bf = *(const short8*)(lwbase + kk * 64 + koff);
      osum = __builtin_amdgcn_mfma_f32_16x16x32_bf16(afrag[kk], bf, osum, 0, 0, 0);
    }
    float* ob = out + (size_t)(SD - 1) * (BD * OD) + (size_t)(gid * 16) * OD + m * 16;
    int rr = (lane >> 4) * 4, cc = lane & 15;
    #pragma unroll
    for (int q = 0; q < 4; ++q)
      ob[(size_t)(rr + q) * OD + cc] = osum[q] + lb;
  }
}

// ---------------- launcher ----------------
extern "C" void kernel_launch(void* const* d_in, const int* in_sizes, int n_in,
                              void* d_out, int out_size, void* d_ws, size_t ws_size,
                              hipStream_t stream) {
  const float* C    = (const float*)d_in[0];
  const float* t    = (const float*)d_in[1];
  // d_in[2] = mask (unused by reference)
  const float* Wih  = (const float*)d_in[3];
  const float* Whh  = (const float*)d_in[4];
  const float* bih  = (const float*)d_in[5];
  const float* bhh  = (const float*)d_in[6];
  const float* linW = (const float*)d_in[7];
  const float* linb = (const float*)d_in[8];
  const float* tW   = (const float*)d_in[9];
  const float* tb   = (const float*)d_in[10];
  float* out = (float*)d_out;

  char* ws = (char*)d_ws;
  float*          CW    = (float*)(ws + 0);                 // 2,097,152
  float*          u     = (float*)(ws + 2097152);           // 8,192
  float*          ub    = (float*)(ws + 2105344);           // 8,192
  float*          td    = (float*)(ws + 2113536);           // 524,288
  unsigned short* whhb  = (unsigned short*)(ws + 2637824);  // 2,097,152
  unsigned short* linwb = (unsigned short*)(ws + 4734976);  // 131,072
  unsigned short* hbuf  = (unsigned short*)(ws + 4866048);  // 524,288
  unsigned int*   flagw = (unsigned int*)(ws + 5390336);    // 16*64*4 = 4,096
  if (ws_size < 5394432) return;

  hipMemsetAsync(flagw, 0, 16 * 64 * 4, stream);
  k_cvt<<<4096, 256, 0, stream>>>(Whh, linW, whhb, linwb);
  k_td <<<512, 256, 0, stream>>>(t, td);
  k_u  <<<8, 256, 0, stream>>>(Wih, tW, tb, bih, bhh, u, ub);
  k_cw <<<dim3(32, 16), 1024, 0, stream>>>(C, Wih, ub, CW);
  k_main<<<256, 256, 0, stream>>>(CW, u, td, whhb, linwb, linb, hbuf, flagw, out);
}

// Round 6
// 2173.853 us; speedup vs baseline: 9.0706x; 1.0553x over previous
//
#include <hip/hip_runtime.h>
#include <stdint.h>

// LSTMTimeDecoder on MI355X — round 6.
// Round 5's NaN was NOT the exchange protocol: splitting global_load and
// s_waitcnt into separate asm blocks let hipcc schedule the sentinel compare
// between load-issue and waitcnt (rule #18: no VMEM scoreboard interlock), so
// badchk read STALE registers and accepted garbage. Fix: loads + vmcnt(0)
// fused in ONE asm block (early-clobber outputs) + sched_barrier(0).
// Protocol (unchanged): h slots pre-poisoned with 0xFF80FF80 (bf16 -inf pair,
// unreachable since |h|<1); consumers load and retry sentinel words — no
// flags, no producer drain; 3-slot rotation with re-poison of slot (t-1)%3
// at step t (provably consumed; ordered by the vmcnt(0) before the h store).

#define HD 512
#define BD 256
#define SD 512
#define OD 128
#define SENT 0xFF80FF80u

typedef __attribute__((ext_vector_type(8))) short short8;
typedef __attribute__((ext_vector_type(4))) float f32x4;
typedef __attribute__((ext_vector_type(4))) unsigned int u32x4;

static __device__ __forceinline__ unsigned short f2bf(float x) {
  unsigned int u = __float_as_uint(x);
  u += 0x7fffu + ((u >> 16) & 1u);
  return (unsigned short)(u >> 16);
}
static __device__ __forceinline__ float sigm(float x) {
  return 1.0f / (1.0f + __expf(-x));
}
static __device__ __forceinline__ float tanhf_(float x) {
  x = fminf(15.f, fmaxf(-15.f, x));
  float e = __expf(2.f * x);
  return (e - 1.f) / (e + 1.f);
}
static __device__ __forceinline__ int badchk(u32x4 v) {
  return (v.x == SENT) | (v.y == SENT) | (v.z == SENT) | (v.w == SENT);
}

// ---------------- prep kernels ----------------
__global__ __launch_bounds__(256) void k_cvt(const float* __restrict__ whh,
                                             const float* __restrict__ linw,
                                             unsigned short* __restrict__ whhb,
                                             unsigned short* __restrict__ linwb) {
  int i = blockIdx.x * 256 + threadIdx.x;
  whhb[i] = f2bf(whh[i]);
  if (i < OD * HD) linwb[i] = f2bf(linw[i]);
}

__global__ __launch_bounds__(256) void k_u(const float* __restrict__ wih,
                                           const float* __restrict__ tw,
                                           const float* __restrict__ tb,
                                           const float* __restrict__ bih,
                                           const float* __restrict__ bhh,
                                           float* __restrict__ u,
                                           float* __restrict__ ub) {
  int gc = blockIdx.x * 256 + threadIdx.x;
  const float4* w4 = (const float4*)(wih + (size_t)gc * (2 * HD) + HD);
  const float4* t4 = (const float4*)tw;
  const float4* b4 = (const float4*)tb;
  float a = 0.f, b = 0.f;
  for (int k = 0; k < HD / 4; ++k) {
    float4 w = w4[k], tv = t4[k], bv = b4[k];
    a += w.x * tv.x + w.y * tv.y + w.z * tv.z + w.w * tv.w;
    b += w.x * bv.x + w.y * bv.y + w.z * bv.z + w.w * bv.w;
  }
  u[gc] = a;
  ub[gc] = b + bih[gc] + bhh[gc];
}

__global__ __launch_bounds__(1024) void k_cw(const float* __restrict__ C,
                                             const float* __restrict__ wih,
                                             const float* __restrict__ ub,
                                             float* __restrict__ CW) {
  int gc = blockIdx.x * 64 + (threadIdx.x & 63);
  int b  = blockIdx.y * 16 + (threadIdx.x >> 6);
  const float4* c4 = (const float4*)(C + (size_t)b * HD);
  const float4* w4 = (const float4*)(wih + (size_t)gc * (2 * HD));
  float acc = 0.f;
  for (int k = 0; k < HD / 4; ++k) {
    float4 cv = c4[k], wv = w4[k];
    acc += cv.x * wv.x + cv.y * wv.y + cv.z * wv.z + cv.w * wv.w;
  }
  CW[(size_t)b * (4 * HD) + gc] = acc + ub[gc];
}

// sentinel-poison the whole h exchange buffer (every launch => replay-safe)
__global__ __launch_bounds__(256) void k_poison(unsigned int* __restrict__ hbuf) {
  u32x4 s = {SENT, SENT, SENT, SENT};
  unsigned int* p = hbuf + (size_t)(blockIdx.x * 256 + threadIdx.x) * 4;
  asm volatile("global_store_dwordx4 %0, %1, off sc0 sc1" :: "v"(p), "v"(s) : "memory");
}

// ---------------- main recurrent kernel ----------------
__global__ __launch_bounds__(256, 1) void k_main(
    const float* __restrict__ CW, const float* __restrict__ u,
    const float* __restrict__ tarr, const unsigned short* __restrict__ whhb,
    const unsigned short* __restrict__ linwb, const float* __restrict__ linb,
    unsigned short* __restrict__ hbuf, float* __restrict__ out)
{
  __shared__ __align__(16) unsigned short Wlds[128 * HD]; // 128KB, swizzled
  __shared__ __align__(16) unsigned short hlds[16 * HD];  // 16KB, swizzled
  __shared__ float gbuf[4][16][33];

  const int tid  = threadIdx.x;
  const int lane = tid & 63;
  const int wv   = tid >> 6;          // wave 0..3 == gate type i,f,g,o
  const int gid  = blockIdx.x & 15;   // batch group
  const int m    = blockIdx.x >> 4;   // member: owns h-cols [m*32, m*32+32)

  // --- stage W_hh slice into LDS (XOR-swizzled 16B chunks) ---
  for (int i = tid; i < 128 * 64; i += 256) {
    int rl = i >> 6, c = i & 63;
    int gr = ((rl >> 5) * HD) + m * 32 + (rl & 31);
    int cs = c ^ (rl & 7);
    *(short8*)((char*)Wlds + (size_t)rl * 1024 + (size_t)c * 16) =
        *(const short8*)((const char*)whhb + (size_t)gr * 1024 + (size_t)cs * 16);
  }

  // --- step-invariant per-thread state ---
  const int r    = tid >> 4;
  const int jl0  = (tid & 15) * 2;
  const int grow = gid * 16 + r;
  float cwr[8], ur[8];
  #pragma unroll
  for (int g = 0; g < 4; ++g) {
    int col = g * HD + m * 32 + jl0;
    cwr[g * 2]     = CW[(size_t)grow * (4 * HD) + col];
    cwr[g * 2 + 1] = CW[(size_t)grow * (4 * HD) + col + 1];
    ur[g * 2]      = u[col];
    ur[g * 2 + 1]  = u[col + 1];
  }
  float c0 = 0.f, c1 = 0.f;

  const int wsel = 1 + (m % 3);       // designated out-projection wave (1..3)
  float lb = 0.f;
  const char* lwbase = nullptr;
  if (m < 8) {
    int oc = m * 16 + (lane & 15);
    lb = linb[oc];
    lwbase = (const char*)linwb + (size_t)oc * 1024;
  }

  short8 afrag[16];
  {
    short8 z = {0, 0, 0, 0, 0, 0, 0, 0};
    #pragma unroll
    for (int kk = 0; kk < 16; ++kk) afrag[kk] = z;   // h_0 = 0
  }

  // hbuf: [16 groups][3 slots][16 rows][512] bf16 ; slot(h_n) = n%3
  char* hb = (char*)(hbuf) + (size_t)gid * (3 * 16 * HD * 2);

  const int row0 = wv * 32 + (lane & 15);
  const int row1 = row0 + 16;
  const int sw0  = (row0 & 7) << 4;
  const int sw1  = (row1 & 7) << 4;
  const int koff = (lane >> 4) * 16;
  const int arow = lane & 15;
  const int asw  = (arow & 7) << 4;

  float tcur = tarr[grow];   // t[0, b]
  float tdv  = 0.f;          // delta for step 0 is 0 by construction

  __syncthreads();

  int sN = 1;                // (t+1)%3

  for (int t = 0; t < SD; ++t) {
    const int sP = (sN + 1 == 3) ? 0 : sN + 1;   // == (t-1)%3 for t>=2
    const size_t soN = (size_t)sN * 16384;

    // ---- re-poison h_{t-1}'s slot (my 1/16): consumed by all (see header) ----
    if (t >= 2) {
      unsigned int* pp = (unsigned int*)(hb + (size_t)sP * 16384 + m * 1024 + tid * 4);
      unsigned int s = SENT;
      asm volatile("global_store_dword %0, %1, off sc0 sc1" :: "v"(pp), "v"(s) : "memory");
    }

    // ---- gates = h_t @ Whh_slice^T ----
    f32x4 acc0 = {0.f, 0.f, 0.f, 0.f}, acc1 = {0.f, 0.f, 0.f, 0.f};
    #pragma unroll
    for (int kk = 0; kk < 16; ++kk) {
      int kb = kk * 64 + koff;
      short8 b0 = *(const short8*)((const char*)Wlds + (size_t)row0 * 1024 + (kb ^ sw0));
      short8 b1 = *(const short8*)((const char*)Wlds + (size_t)row1 * 1024 + (kb ^ sw1));
      acc0 = __builtin_amdgcn_mfma_f32_16x16x32_bf16(afrag[kk], b0, acc0, 0, 0, 0);
      acc1 = __builtin_amdgcn_mfma_f32_16x16x32_bf16(afrag[kk], b1, acc1, 0, 0, 0);
    }
    {
      int rr = (lane >> 4) * 4, cc = lane & 15;
      #pragma unroll
      for (int q = 0; q < 4; ++q) {
        gbuf[wv][rr + q][cc]      = acc0[q];
        gbuf[wv][rr + q][16 + cc] = acc1[q];
      }
    }
    __syncthreads();  // B1: gates visible in gbuf

    // ---- LSTM cell update (2 elements/thread) ----
    {
      float p0i = gbuf[0][r][jl0]     + cwr[0] + tdv * ur[0];
      float p1i = gbuf[0][r][jl0 + 1] + cwr[1] + tdv * ur[1];
      float p0f = gbuf[1][r][jl0]     + cwr[2] + tdv * ur[2];
      float p1f = gbuf[1][r][jl0 + 1] + cwr[3] + tdv * ur[3];
      float p0g = gbuf[2][r][jl0]     + cwr[4] + tdv * ur[4];
      float p1g = gbuf[2][r][jl0 + 1] + cwr[5] + tdv * ur[5];
      float p0o = gbuf[3][r][jl0]     + cwr[6] + tdv * ur[6];
      float p1o = gbuf[3][r][jl0 + 1] + cwr[7] + tdv * ur[7];
      c0 = sigm(p0f) * c0 + sigm(p0i) * tanhf_(p0g);
      c1 = sigm(p1f) * c1 + sigm(p1i) * tanhf_(p1g);
      float h0 = sigm(p0o) * tanhf_(c0);
      float h1 = sigm(p1o) * tanhf_(c1);
      unsigned int hp = (unsigned int)f2bf(h0) | ((unsigned int)f2bf(h1) << 16);
      // order: re-poison (old slot) must be at L3 before this store is visible
      asm volatile("s_waitcnt vmcnt(0)" ::: "memory");
      unsigned int* hslot = (unsigned int*)(hb + soN + (size_t)(r * HD + m * 32 + jl0) * 2);
      asm volatile("global_store_dword %0, %1, off sc0 sc1" :: "v"(hslot), "v"(hp) : "memory");
    }

    // prefetch next t value (consumed at loop bottom)
    float tn = (t + 1 < SD) ? tarr[(size_t)(t + 1) * BD + grow] : 0.f;

    // ---- out row t-1 (afrag = h_t), issued AFTER h store so peers aren't
    //      delayed; its latency rides the poll window ----
    if (wv == wsel && m < 8 && t > 0) {
      f32x4 osum = {0.f, 0.f, 0.f, 0.f};
      #pragma unroll
      for (int kk = 0; kk < 16; ++kk) {
        short8 bf = *(const short8*)(lwbase + kk * 64 + koff);
        osum = __builtin_amdgcn_mfma_f32_16x16x32_bf16(afrag[kk], bf, osum, 0, 0, 0);
      }
      float* ob = out + (size_t)(t - 1) * (BD * OD) + (size_t)(gid * 16) * OD + m * 16;
      int rr = (lane >> 4) * 4, cc = lane & 15;
      #pragma unroll
      for (int q = 0; q < 4; ++q)
        ob[(size_t)(rr + q) * OD + cc] = osum[q] + lb;
    }

    // ---- fused poll+reload of h_{t+1}: self-validating sentinel retry.
    //      Loads + vmcnt(0) in ONE asm block (early-clobber outputs) so the
    //      data is architecturally in the registers before any C++ use
    //      can be scheduled (rule #18 hazard from round 5). ----
    u32x4 v0, v1, v2, v3;
    {
      const char* src = hb + soN + (size_t)tid * 16;
      int guard = 0;
      for (;;) {
        asm volatile(
            "global_load_dwordx4 %0, %4, off sc0 sc1\n\t"
            "global_load_dwordx4 %1, %5, off sc0 sc1\n\t"
            "global_load_dwordx4 %2, %6, off sc0 sc1\n\t"
            "global_load_dwordx4 %3, %7, off sc0 sc1\n\t"
            "s_waitcnt vmcnt(0)"
            : "=&v"(v0), "=&v"(v1), "=&v"(v2), "=&v"(v3)
            : "v"(src), "v"(src + 4096), "v"(src + 8192), "v"(src + 12288)
            : "memory");
        __builtin_amdgcn_sched_barrier(0);
        if (!(badchk(v0) | badchk(v1) | badchk(v2) | badchk(v3))) break;
        if (++guard > (1 << 14)) break;  // bounded: garbage-not-hang
      }
    }
    __builtin_amdgcn_sched_barrier(0);

    // ---- scatter h_{t+1} into LDS (swizzled) ----
    {
      const int c = tid & 63;
      { int rr = wv;      *(u32x4*)((char*)hlds + (size_t)rr * 1024 + (size_t)((c ^ (rr & 7)) * 16)) = v0; }
      { int rr = wv + 4;  *(u32x4*)((char*)hlds + (size_t)rr * 1024 + (size_t)((c ^ (rr & 7)) * 16)) = v1; }
      { int rr = wv + 8;  *(u32x4*)((char*)hlds + (size_t)rr * 1024 + (size_t)((c ^ (rr & 7)) * 16)) = v2; }
      { int rr = wv + 12; *(u32x4*)((char*)hlds + (size_t)rr * 1024 + (size_t)((c ^ (rr & 7)) * 16)) = v3; }
    }
    __syncthreads();  // B4: hlds ready

    // ---- refresh A-frags (h_{t+1}) ----
    #pragma unroll
    for (int kk = 0; kk < 16; ++kk) {
      int kb = kk * 64 + koff;
      afrag[kk] = *(const short8*)((const char*)hlds + (size_t)arow * 1024 + (kb ^ asw));
    }

    // ---- advance time delta ----
    tdv  = tn - tcur;
    tcur = tn;
    sN   = (sN + 1 == 3) ? 0 : sN + 1;
  }

  // ---- tail: out row SD-1 (afrag = h_SD) ----
  if (m < 8 && wv == wsel) {
    f32x4 osum = {0.f, 0.f, 0.f, 0.f};
    #pragma unroll
    for (int kk = 0; kk < 16; ++kk) {
      short8 bf = *(const short8*)(lwbase + kk * 64 + koff);
      osum = __builtin_amdgcn_mfma_f32_16x16x32_bf16(afrag[kk], bf, osum, 0, 0, 0);
    }
    float* ob = out + (size_t)(SD - 1) * (BD * OD) + (size_t)(gid * 16) * OD + m * 16;
    int rr = (lane >> 4) * 4, cc = lane & 15;
    #pragma unroll
    for (int q = 0; q < 4; ++q)
      ob[(size_t)(rr + q) * OD + cc] = osum[q] + lb;
  }
}

// ---------------- launcher ----------------
extern "C" void kernel_launch(void* const* d_in, const int* in_sizes, int n_in,
                              void* d_out, int out_size, void* d_ws, size_t ws_size,
                              hipStream_t stream) {
  const float* C    = (const float*)d_in[0];
  const float* t    = (const float*)d_in[1];
  // d_in[2] = mask (unused by reference)
  const float* Wih  = (const float*)d_in[3];
  const float* Whh  = (const float*)d_in[4];
  const float* bih  = (const float*)d_in[5];
  const float* bhh  = (const float*)d_in[6];
  const float* linW = (const float*)d_in[7];
  const float* linb = (const float*)d_in[8];
  const float* tW   = (const float*)d_in[9];
  const float* tb   = (const float*)d_in[10];
  float* out = (float*)d_out;

  char* ws = (char*)d_ws;
  float*          CW    = (float*)(ws + 0);                 // 2,097,152
  float*          u     = (float*)(ws + 2097152);           // 8,192
  float*          ub    = (float*)(ws + 2105344);           // 8,192
  unsigned short* whhb  = (unsigned short*)(ws + 2113536);  // 2,097,152
  unsigned short* linwb = (unsigned short*)(ws + 4210688);  // 131,072
  unsigned short* hbuf  = (unsigned short*)(ws + 4341760);  // 16*3*16*512*2 = 786,432
  if (ws_size < 5128192) return;

  k_poison<<<192, 256, 0, stream>>>((unsigned int*)hbuf);
  k_cvt<<<4096, 256, 0, stream>>>(Whh, linW, whhb, linwb);
  k_u  <<<8, 256, 0, stream>>>(Wih, tW, tb, bih, bhh, u, ub);
  k_cw <<<dim3(32, 16), 1024, 0, stream>>>(C, Wih, ub, CW);
  k_main<<<256, 256, 0, stream>>>(CW, u, t, whhb, linwb, linb, hbuf, out);
}